// Round 2
// baseline (5675.108 us; speedup 1.0000x reference)
//
#include <hip/hip_runtime.h>
#include <math.h>

#define NN 100000     // nodes
#define NE 1600000    // edges
#define D  128        // feature dim
#define NL 3          // layers

// ---------------- degree / normalization ----------------

__global__ __launch_bounds__(256) void k_count(const int* __restrict__ dstv,
                                               unsigned* __restrict__ deg) {
  int i = blockIdx.x * 256 + threadIdx.x;
  if (i < NE) atomicAdd(&deg[dstv[i]], 1u);
}

__global__ __launch_bounds__(256) void k_dinv(const unsigned* __restrict__ deg,
                                              float* __restrict__ dinv) {
  int i = blockIdx.x * 256 + threadIdx.x;
  if (i < NN) dinv[i] = 1.0f / sqrtf((float)(deg[i] + 1u));
}

// ---------------- CSR build: 3-stage exclusive scan ----------------

__global__ __launch_bounds__(256) void k_scan1(const unsigned* __restrict__ deg,
                                               unsigned* __restrict__ bsum) {
  __shared__ unsigned s[256];
  int t = threadIdx.x;
  int i = blockIdx.x * 256 + t;
  s[t] = (i < NN) ? deg[i] : 0u;
  __syncthreads();
  for (int off = 128; off > 0; off >>= 1) {
    if (t < off) s[t] += s[t + off];
    __syncthreads();
  }
  if (t == 0) bsum[blockIdx.x] = s[0];
}

__global__ __launch_bounds__(512) void k_scan2(const unsigned* __restrict__ bsum,
                                               unsigned* __restrict__ boff, int nb) {
  __shared__ unsigned s[512];
  int t = threadIdx.x;
  unsigned v = (t < nb) ? bsum[t] : 0u;
  s[t] = v;
  __syncthreads();
  for (int off = 1; off < 512; off <<= 1) {
    unsigned x = (t >= off) ? s[t - off] : 0u;
    __syncthreads();
    s[t] += x;
    __syncthreads();
  }
  if (t < nb) boff[t] = s[t] - v;   // exclusive
}

__global__ __launch_bounds__(256) void k_scan3(const unsigned* __restrict__ deg,
                                               const unsigned* __restrict__ boff,
                                               unsigned* __restrict__ rowptr) {
  __shared__ unsigned s[256];
  int t = threadIdx.x;
  int i = blockIdx.x * 256 + t;
  unsigned v = (i < NN) ? deg[i] : 0u;
  s[t] = v;
  __syncthreads();
  for (int off = 1; off < 256; off <<= 1) {
    unsigned x = (t >= off) ? s[t - off] : 0u;
    __syncthreads();
    s[t] += x;
    __syncthreads();
  }
  unsigned excl = s[t] - v + boff[blockIdx.x];
  if (i <= NN) rowptr[i] = excl;    // i==NN lands exactly on total == NE
}

__global__ __launch_bounds__(256) void k_fill(const int* __restrict__ srcv,
                                              const int* __restrict__ dstv,
                                              const float* __restrict__ dinv,
                                              const unsigned* __restrict__ rowptr,
                                              unsigned* __restrict__ fillcnt,
                                              int* __restrict__ colv,
                                              float* __restrict__ enorm) {
  int i = blockIdx.x * 256 + threadIdx.x;
  if (i >= NE) return;
  int d = dstv[i];
  int s = srcv[i];
  unsigned pos = rowptr[d] + atomicAdd(&fillcnt[d], 1u);
  colv[pos] = s;
  enorm[pos] = dinv[s] * dinv[d];
}

// ---------------- GEMM: hw = h @ W  (f32 vector ALU, W in LDS) ----------------
// Block: 512 threads (8 waves), 128 rows per block; 64 KB LDS -> 2 blocks/CU
// = 16 waves/CU. Each wave: 16 rows in 4 groups of 4; each lane computes
// 4 rows x 2 cols (cols 2*lane, 2*lane+1). k chunked by 8 to keep the
// A-broadcast buffer at 32 VGPRs (round-1 spill was hv[4][16]=64 regs).

__global__ __launch_bounds__(512) void k_gemm(const float* __restrict__ A,
                                              const float* __restrict__ W,
                                              float* __restrict__ Bout) {
  __shared__ float Wl[D * D];   // 64 KB
  const int t = threadIdx.x;
#pragma unroll
  for (int i = 0; i < 8; ++i) {
    int off = (t + i * 512) * 4;
    *(float4*)&Wl[off] = *(const float4*)&W[off];
  }
  __syncthreads();

  const int wave = t >> 6, lane = t & 63;
  const int row0 = blockIdx.x * 128 + wave * 16;

  for (int g = 0; g < 4; ++g) {
    const int r0 = row0 + g * 4;
    float acc[4][2];
#pragma unroll
    for (int r = 0; r < 4; ++r) { acc[r][0] = 0.f; acc[r][1] = 0.f; }

    const float* Ar[4];
#pragma unroll
    for (int r = 0; r < 4; ++r) {
      int rr = r0 + r;
      if (rr > NN - 1) rr = NN - 1;           // clamp reads; writes guarded
      Ar[r] = A + (size_t)rr * D;
    }

    for (int kc = 0; kc < D; kc += 8) {
      float hv[4][8];                          // 32 VGPRs in flight
#pragma unroll
      for (int r = 0; r < 4; ++r) {
#pragma unroll
        for (int q = 0; q < 2; ++q)
          *(float4*)&hv[r][q * 4] = *(const float4*)&Ar[r][kc + q * 4];
      }
#pragma unroll
      for (int kk = 0; kk < 8; ++kk) {
        const float2 wv = *(const float2*)&Wl[(kc + kk) * D + lane * 2];
#pragma unroll
        for (int r = 0; r < 4; ++r) {
          acc[r][0] = fmaf(hv[r][kk], wv.x, acc[r][0]);
          acc[r][1] = fmaf(hv[r][kk], wv.y, acc[r][1]);
        }
      }
    }

#pragma unroll
    for (int r = 0; r < 4; ++r) {
      int rr = r0 + r;
      if (rr < NN) {
        float2 o; o.x = acc[r][0]; o.y = acc[r][1];
        *(float2*)&Bout[(size_t)rr * D + lane * 2] = o;
      }
    }
  }
}

// ---------------- Aggregation: one wave per node, fused bias+ReLU ----------------

__global__ __launch_bounds__(256) void k_agg(const float* __restrict__ hw,
                                             const int* __restrict__ colv,
                                             const float* __restrict__ enorm,
                                             const unsigned* __restrict__ rowptr,
                                             const float* __restrict__ dinv,
                                             const float* __restrict__ bias,
                                             float* __restrict__ hout) {
  const int wid = (blockIdx.x * 256 + threadIdx.x) >> 6;   // node id
  const int lane = threadIdx.x & 63;
  if (wid >= NN) return;

  const float di = dinv[wid];
  const float sn = di * di;
  float2 v = *(const float2*)&hw[(size_t)wid * D + lane * 2];
  float ax = v.x * sn, ay = v.y * sn;

  const unsigned s = rowptr[wid], e = rowptr[wid + 1];
  for (unsigned j = s; j < e; ++j) {
    const int src = colv[j];          // wave-uniform load
    const float w = enorm[j];         // wave-uniform load
    const float2 u = *(const float2*)&hw[(size_t)src * D + lane * 2];
    ax = fmaf(w, u.x, ax);
    ay = fmaf(w, u.y, ay);
  }

  const float2 b = *(const float2*)&bias[lane * 2];
  ax += b.x; ay += b.y;
  ax = ax > 0.f ? ax : 0.f;
  ay = ay > 0.f ? ay : 0.f;
  float2 o; o.x = ax; o.y = ay;
  *(float2*)&hout[(size_t)wid * D + lane * 2] = o;
}

// ---------------- Head GEMV: out = h @ head_W + head_b ----------------

__global__ __launch_bounds__(256) void k_head(const float* __restrict__ h,
                                              const float* __restrict__ hW,
                                              const float* __restrict__ hb,
                                              float* __restrict__ out) {
  const int wid = (blockIdx.x * 256 + threadIdx.x) >> 6;
  const int lane = threadIdx.x & 63;
  if (wid >= NN) return;
  const float* hr = h + (size_t)wid * D;
  float sum = hr[lane] * hW[lane] + hr[lane + 64] * hW[lane + 64];
#pragma unroll
  for (int off = 32; off > 0; off >>= 1) sum += __shfl_down(sum, off, 64);
  if (lane == 0) out[wid] = sum + hb[0];
}

// ---------------- launch ----------------

extern "C" void kernel_launch(void* const* d_in, const int* in_sizes, int n_in,
                              void* d_out, int out_size, void* d_ws, size_t ws_size,
                              hipStream_t stream) {
  const float* x   = (const float*)d_in[0];
  const int*   ei  = (const int*)d_in[1];
  const float* Ws  = (const float*)d_in[2];
  const float* bs  = (const float*)d_in[3];
  const float* hW  = (const float*)d_in[4];
  const float* hb  = (const float*)d_in[5];
  float* out = (float*)d_out;

  char* w = (char*)d_ws;
  float*    bufA    = (float*)w;    w += (size_t)NN * D * 4;       // 51.2 MB
  float*    bufB    = (float*)w;    w += (size_t)NN * D * 4;       // 51.2 MB
  int*      colv    = (int*)w;      w += (size_t)NE * 4;           // 6.4 MB
  float*    enorm   = (float*)w;    w += (size_t)NE * 4;           // 6.4 MB
  unsigned* rowptr  = (unsigned*)w; w += (size_t)(NN + 16) * 4;
  unsigned* deg     = (unsigned*)w; w += (size_t)NN * 4;
  unsigned* fillcnt = (unsigned*)w; w += (size_t)NN * 4;
  float*    dinv    = (float*)w;    w += (size_t)NN * 4;
  unsigned* bsum    = (unsigned*)w; w += 512 * 4;
  unsigned* boff    = (unsigned*)w; w += 512 * 4;

  const int* srcv = ei;
  const int* dstv = ei + NE;

  hipMemsetAsync(deg,     0, (size_t)NN * 4, stream);
  hipMemsetAsync(fillcnt, 0, (size_t)NN * 4, stream);

  const int NB = (NN + 255) / 256;   // 391

  k_count<<<(NE + 255) / 256, 256, 0, stream>>>(dstv, deg);
  k_dinv <<<NB, 256, 0, stream>>>(deg, dinv);
  k_scan1<<<NB, 256, 0, stream>>>(deg, bsum);
  k_scan2<<<1, 512, 0, stream>>>(bsum, boff, NB);
  k_scan3<<<NB, 256, 0, stream>>>(deg, boff, rowptr);
  k_fill <<<(NE + 255) / 256, 256, 0, stream>>>(srcv, dstv, dinv, rowptr, fillcnt, colv, enorm);

  const float* hin = x;
  for (int l = 0; l < NL; ++l) {
    k_gemm<<<(NN + 127) / 128, 512, 0, stream>>>(hin, Ws + (size_t)l * D * D, bufA);
    k_agg <<<(NN + 3) / 4, 256, 0, stream>>>(bufA, colv, enorm, rowptr, dinv,
                                             bs + (size_t)l * D, bufB);
    hin = bufB;
  }

  k_head<<<(NN + 3) / 4, 256, 0, stream>>>(bufB, hW, hb, out);
}

// Round 3
// 1063.509 us; speedup vs baseline: 5.3362x; 5.3362x over previous
//
#include <hip/hip_runtime.h>
#include <math.h>

#define NN 100000     // nodes
#define NE 1600000    // edges
#define D  128        // feature dim
#define NL 3          // layers

// ---------------- degree / normalization ----------------

__global__ __launch_bounds__(256) void k_count(const int* __restrict__ dstv,
                                               unsigned* __restrict__ deg) {
  int i = blockIdx.x * 256 + threadIdx.x;
  if (i < NE) atomicAdd(&deg[dstv[i]], 1u);
}

__global__ __launch_bounds__(256) void k_dinv(const unsigned* __restrict__ deg,
                                              float* __restrict__ dinv) {
  int i = blockIdx.x * 256 + threadIdx.x;
  if (i < NN) dinv[i] = 1.0f / sqrtf((float)(deg[i] + 1u));
}

// ---------------- CSR build: 3-stage exclusive scan ----------------

__global__ __launch_bounds__(256) void k_scan1(const unsigned* __restrict__ deg,
                                               unsigned* __restrict__ bsum) {
  __shared__ unsigned s[256];
  int t = threadIdx.x;
  int i = blockIdx.x * 256 + t;
  s[t] = (i < NN) ? deg[i] : 0u;
  __syncthreads();
  for (int off = 128; off > 0; off >>= 1) {
    if (t < off) s[t] += s[t + off];
    __syncthreads();
  }
  if (t == 0) bsum[blockIdx.x] = s[0];
}

__global__ __launch_bounds__(512) void k_scan2(const unsigned* __restrict__ bsum,
                                               unsigned* __restrict__ boff, int nb) {
  __shared__ unsigned s[512];
  int t = threadIdx.x;
  unsigned v = (t < nb) ? bsum[t] : 0u;
  s[t] = v;
  __syncthreads();
  for (int off = 1; off < 512; off <<= 1) {
    unsigned x = (t >= off) ? s[t - off] : 0u;
    __syncthreads();
    s[t] += x;
    __syncthreads();
  }
  if (t < nb) boff[t] = s[t] - v;   // exclusive
}

__global__ __launch_bounds__(256) void k_scan3(const unsigned* __restrict__ deg,
                                               const unsigned* __restrict__ boff,
                                               unsigned* __restrict__ rowptr) {
  __shared__ unsigned s[256];
  int t = threadIdx.x;
  int i = blockIdx.x * 256 + t;
  unsigned v = (i < NN) ? deg[i] : 0u;
  s[t] = v;
  __syncthreads();
  for (int off = 1; off < 256; off <<= 1) {
    unsigned x = (t >= off) ? s[t - off] : 0u;
    __syncthreads();
    s[t] += x;
    __syncthreads();
  }
  unsigned excl = s[t] - v + boff[blockIdx.x];
  if (i <= NN) rowptr[i] = excl;    // i==NN lands exactly on total == NE
}

__global__ __launch_bounds__(256) void k_fill(const int* __restrict__ srcv,
                                              const int* __restrict__ dstv,
                                              const float* __restrict__ dinv,
                                              const unsigned* __restrict__ rowptr,
                                              unsigned* __restrict__ fillcnt,
                                              int* __restrict__ colv,
                                              float* __restrict__ enorm) {
  int i = blockIdx.x * 256 + threadIdx.x;
  if (i >= NE) return;
  int d = dstv[i];
  int s = srcv[i];
  unsigned pos = rowptr[d] + atomicAdd(&fillcnt[d], 1u);
  colv[pos] = s;
  enorm[pos] = dinv[s] * dinv[d];
}

// ---------------- GEMM: hw = h @ W  (f32 vector ALU, W in LDS) ----------------
// 512 threads (8 waves), 128 rows/block, 64 KB LDS -> 2 blocks/CU = 4 waves/SIMD.
// Each wave: 16 rows in 4 groups of 4; each lane computes 4 rows x 2 cols
// (cols lane and lane+64 -> 2-way LDS bank aliasing = free, ds_read2-able).
// k loop: unroll 1, no staging arrays -> ~64 live VGPRs, no scratch.

__global__ __launch_bounds__(512, 4) void k_gemm(const float* __restrict__ A,
                                                 const float* __restrict__ W,
                                                 float* __restrict__ Bout) {
  __shared__ float Wl[D * D];   // 64 KB
  const int t = threadIdx.x;
#pragma unroll
  for (int i = 0; i < 8; ++i) {
    int off = (t + i * 512) * 4;
    *(float4*)&Wl[off] = *(const float4*)&W[off];
  }
  __syncthreads();

  const int wave = t >> 6, lane = t & 63;
  const int row0 = blockIdx.x * 128 + wave * 16;

#pragma unroll 1
  for (int g = 0; g < 4; ++g) {
    const int r0 = row0 + g * 4;
    int rr0 = r0 + 0; if (rr0 > NN - 1) rr0 = NN - 1;   // clamp reads
    int rr1 = r0 + 1; if (rr1 > NN - 1) rr1 = NN - 1;
    int rr2 = r0 + 2; if (rr2 > NN - 1) rr2 = NN - 1;
    int rr3 = r0 + 3; if (rr3 > NN - 1) rr3 = NN - 1;
    const float* Ar0 = A + (size_t)rr0 * D;
    const float* Ar1 = A + (size_t)rr1 * D;
    const float* Ar2 = A + (size_t)rr2 * D;
    const float* Ar3 = A + (size_t)rr3 * D;

    float a0x = 0.f, a0y = 0.f, a1x = 0.f, a1y = 0.f;
    float a2x = 0.f, a2y = 0.f, a3x = 0.f, a3y = 0.f;

#pragma unroll 1
    for (int kc = 0; kc < D; kc += 4) {
      const float4 h0 = *(const float4*)(Ar0 + kc);
      const float4 h1 = *(const float4*)(Ar1 + kc);
      const float4 h2 = *(const float4*)(Ar2 + kc);
      const float4 h3 = *(const float4*)(Ar3 + kc);
#pragma unroll
      for (int kk = 0; kk < 4; ++kk) {
        const float wx = Wl[(kc + kk) * D + lane];
        const float wy = Wl[(kc + kk) * D + 64 + lane];
        const float e0 = ((const float*)&h0)[kk];
        const float e1 = ((const float*)&h1)[kk];
        const float e2 = ((const float*)&h2)[kk];
        const float e3 = ((const float*)&h3)[kk];
        a0x = fmaf(e0, wx, a0x);  a0y = fmaf(e0, wy, a0y);
        a1x = fmaf(e1, wx, a1x);  a1y = fmaf(e1, wy, a1y);
        a2x = fmaf(e2, wx, a2x);  a2y = fmaf(e2, wy, a2y);
        a3x = fmaf(e3, wx, a3x);  a3y = fmaf(e3, wy, a3y);
      }
    }

    if (r0 + 0 < NN) { Bout[(size_t)(r0+0) * D + lane] = a0x; Bout[(size_t)(r0+0) * D + 64 + lane] = a0y; }
    if (r0 + 1 < NN) { Bout[(size_t)(r0+1) * D + lane] = a1x; Bout[(size_t)(r0+1) * D + 64 + lane] = a1y; }
    if (r0 + 2 < NN) { Bout[(size_t)(r0+2) * D + lane] = a2x; Bout[(size_t)(r0+2) * D + 64 + lane] = a2y; }
    if (r0 + 3 < NN) { Bout[(size_t)(r0+3) * D + lane] = a3x; Bout[(size_t)(r0+3) * D + 64 + lane] = a3y; }
  }
}

// ---------------- Aggregation: one wave per node, fused bias+ReLU ----------------

__global__ __launch_bounds__(256) void k_agg(const float* __restrict__ hw,
                                             const int* __restrict__ colv,
                                             const float* __restrict__ enorm,
                                             const unsigned* __restrict__ rowptr,
                                             const float* __restrict__ dinv,
                                             const float* __restrict__ bias,
                                             float* __restrict__ hout) {
  const int wid = (blockIdx.x * 256 + threadIdx.x) >> 6;   // node id
  const int lane = threadIdx.x & 63;
  if (wid >= NN) return;

  const float di = dinv[wid];
  const float sn = di * di;
  float2 v = *(const float2*)&hw[(size_t)wid * D + lane * 2];
  float ax = v.x * sn, ay = v.y * sn;

  const unsigned s = rowptr[wid], e = rowptr[wid + 1];
  for (unsigned j = s; j < e; ++j) {
    const int src = colv[j];          // wave-uniform load
    const float w = enorm[j];         // wave-uniform load
    const float2 u = *(const float2*)&hw[(size_t)src * D + lane * 2];
    ax = fmaf(w, u.x, ax);
    ay = fmaf(w, u.y, ay);
  }

  const float2 b = *(const float2*)&bias[lane * 2];
  ax += b.x; ay += b.y;
  ax = ax > 0.f ? ax : 0.f;
  ay = ay > 0.f ? ay : 0.f;
  float2 o; o.x = ax; o.y = ay;
  *(float2*)&hout[(size_t)wid * D + lane * 2] = o;
}

// ---------------- Head GEMV: out = h @ head_W + head_b ----------------

__global__ __launch_bounds__(256) void k_head(const float* __restrict__ h,
                                              const float* __restrict__ hW,
                                              const float* __restrict__ hb,
                                              float* __restrict__ out) {
  const int wid = (blockIdx.x * 256 + threadIdx.x) >> 6;
  const int lane = threadIdx.x & 63;
  if (wid >= NN) return;
  const float* hr = h + (size_t)wid * D;
  float sum = hr[lane] * hW[lane] + hr[lane + 64] * hW[lane + 64];
#pragma unroll
  for (int off = 32; off > 0; off >>= 1) sum += __shfl_down(sum, off, 64);
  if (lane == 0) out[wid] = sum + hb[0];
}

// ---------------- launch ----------------

extern "C" void kernel_launch(void* const* d_in, const int* in_sizes, int n_in,
                              void* d_out, int out_size, void* d_ws, size_t ws_size,
                              hipStream_t stream) {
  const float* x   = (const float*)d_in[0];
  const int*   ei  = (const int*)d_in[1];
  const float* Ws  = (const float*)d_in[2];
  const float* bs  = (const float*)d_in[3];
  const float* hW  = (const float*)d_in[4];
  const float* hb  = (const float*)d_in[5];
  float* out = (float*)d_out;

  char* w = (char*)d_ws;
  float*    bufA    = (float*)w;    w += (size_t)NN * D * 4;       // 51.2 MB
  float*    bufB    = (float*)w;    w += (size_t)NN * D * 4;       // 51.2 MB
  int*      colv    = (int*)w;      w += (size_t)NE * 4;           // 6.4 MB
  float*    enorm   = (float*)w;    w += (size_t)NE * 4;           // 6.4 MB
  unsigned* rowptr  = (unsigned*)w; w += (size_t)(NN + 16) * 4;
  unsigned* deg     = (unsigned*)w; w += (size_t)NN * 4;
  unsigned* fillcnt = (unsigned*)w; w += (size_t)NN * 4;
  float*    dinv    = (float*)w;    w += (size_t)NN * 4;
  unsigned* bsum    = (unsigned*)w; w += 512 * 4;
  unsigned* boff    = (unsigned*)w; w += 512 * 4;

  const int* srcv = ei;
  const int* dstv = ei + NE;

  hipMemsetAsync(deg,     0, (size_t)NN * 4, stream);
  hipMemsetAsync(fillcnt, 0, (size_t)NN * 4, stream);

  const int NB = (NN + 255) / 256;   // 391

  k_count<<<(NE + 255) / 256, 256, 0, stream>>>(dstv, deg);
  k_dinv <<<NB, 256, 0, stream>>>(deg, dinv);
  k_scan1<<<NB, 256, 0, stream>>>(deg, bsum);
  k_scan2<<<1, 512, 0, stream>>>(bsum, boff, NB);
  k_scan3<<<NB, 256, 0, stream>>>(deg, boff, rowptr);
  k_fill <<<(NE + 255) / 256, 256, 0, stream>>>(srcv, dstv, dinv, rowptr, fillcnt, colv, enorm);

  const float* hin = x;
  for (int l = 0; l < NL; ++l) {
    k_gemm<<<(NN + 127) / 128, 512, 0, stream>>>(hin, Ws + (size_t)l * D * D, bufA);
    k_agg <<<(NN + 3) / 4, 256, 0, stream>>>(bufA, colv, enorm, rowptr, dinv,
                                             bs + (size_t)l * D, bufB);
    hin = bufB;
  }

  k_head<<<(NN + 3) / 4, 256, 0, stream>>>(bufB, hW, hb, out);
}

// Round 4
// 610.431 us; speedup vs baseline: 9.2969x; 1.7422x over previous
//
#include <hip/hip_runtime.h>
#include <math.h>

#define NN 100000     // nodes
#define NE 1600000    // edges
#define D  128        // feature dim
#define NW 64         // u32 words per row (D/2 packed bf16x2)
#define NL 3          // layers

typedef unsigned int u32;

// ---- packed bf16x2 helpers (RNE) ----
__device__ inline float blo(u32 v) { return __uint_as_float(v << 16); }
__device__ inline float bhi(u32 v) { return __uint_as_float(v & 0xffff0000u); }
__device__ inline u32 bpack(float x, float y) {
  u32 xb = __float_as_uint(x), yb = __float_as_uint(y);
  xb = (xb + 0x7fffu + ((xb >> 16) & 1u)) >> 16;
  yb = (yb + 0x7fffu + ((yb >> 16) & 1u)) & 0xffff0000u;
  return xb | yb;
}

// ---------------- degree / normalization ----------------

__global__ __launch_bounds__(256) void k_count(const int* __restrict__ dstv,
                                               unsigned* __restrict__ deg) {
  int i = blockIdx.x * 256 + threadIdx.x;
  if (i < NE) atomicAdd(&deg[dstv[i]], 1u);
}

__global__ __launch_bounds__(256) void k_dinv(const unsigned* __restrict__ deg,
                                              float* __restrict__ dinv) {
  int i = blockIdx.x * 256 + threadIdx.x;
  if (i < NN) dinv[i] = 1.0f / sqrtf((float)(deg[i] + 1u));
}

// ---------------- x -> packed bf16 ----------------

__global__ __launch_bounds__(256) void k_cvt(const float* __restrict__ x,
                                             u32* __restrict__ xb) {
  int i = blockIdx.x * 256 + threadIdx.x;
  if (i < NN * NW) {
    const float2 v = *(const float2*)&x[(size_t)i * 2];
    xb[i] = bpack(v.x, v.y);
  }
}

// ---------------- CSR build: 3-stage exclusive scan ----------------

__global__ __launch_bounds__(256) void k_scan1(const unsigned* __restrict__ deg,
                                               unsigned* __restrict__ bsum) {
  __shared__ unsigned s[256];
  int t = threadIdx.x;
  int i = blockIdx.x * 256 + t;
  s[t] = (i < NN) ? deg[i] : 0u;
  __syncthreads();
  for (int off = 128; off > 0; off >>= 1) {
    if (t < off) s[t] += s[t + off];
    __syncthreads();
  }
  if (t == 0) bsum[blockIdx.x] = s[0];
}

__global__ __launch_bounds__(512) void k_scan2(const unsigned* __restrict__ bsum,
                                               unsigned* __restrict__ boff, int nb) {
  __shared__ unsigned s[512];
  int t = threadIdx.x;
  unsigned v = (t < nb) ? bsum[t] : 0u;
  s[t] = v;
  __syncthreads();
  for (int off = 1; off < 512; off <<= 1) {
    unsigned x = (t >= off) ? s[t - off] : 0u;
    __syncthreads();
    s[t] += x;
    __syncthreads();
  }
  if (t < nb) boff[t] = s[t] - v;   // exclusive
}

__global__ __launch_bounds__(256) void k_scan3(const unsigned* __restrict__ deg,
                                               const unsigned* __restrict__ boff,
                                               unsigned* __restrict__ rowptr) {
  __shared__ unsigned s[256];
  int t = threadIdx.x;
  int i = blockIdx.x * 256 + t;
  unsigned v = (i < NN) ? deg[i] : 0u;
  s[t] = v;
  __syncthreads();
  for (int off = 1; off < 256; off <<= 1) {
    unsigned x = (t >= off) ? s[t - off] : 0u;
    __syncthreads();
    s[t] += x;
    __syncthreads();
  }
  unsigned excl = s[t] - v + boff[blockIdx.x];
  if (i <= NN) rowptr[i] = excl;    // i==NN lands exactly on total == NE
}

__global__ __launch_bounds__(256) void k_fill(const int* __restrict__ srcv,
                                              const int* __restrict__ dstv,
                                              const float* __restrict__ dinv,
                                              const unsigned* __restrict__ rowptr,
                                              unsigned* __restrict__ fillcnt,
                                              uint2* __restrict__ edat) {
  int i = blockIdx.x * 256 + threadIdx.x;
  if (i >= NE) return;
  int d = dstv[i];
  int s = srcv[i];
  unsigned pos = rowptr[d] + atomicAdd(&fillcnt[d], 1u);
  uint2 v; v.x = (u32)s; v.y = __float_as_uint(dinv[s] * dinv[d]);
  edat[pos] = v;   // single 8B scattered write
}

// ---------------- GEMM: hw = h @ W  (f32 VALU, bf16 storage, W f32 in LDS) ----
// 512 threads (8 waves), 128 rows/block, 64 KB LDS -> 2 blocks/CU.
// Each lane: 4 rows x cols (2*lane, 2*lane+1). A-reads are wave-uniform bf16
// uint4 (readfirstlane'd row -> scalar path); accumulate f32; store bf16x2.

__global__ __launch_bounds__(512, 4) void k_gemm(const u32* __restrict__ Ab,
                                                 const float* __restrict__ W,
                                                 u32* __restrict__ Bb) {
  __shared__ float Wl[D * D];   // 64 KB
  const int t = threadIdx.x;
#pragma unroll
  for (int i = 0; i < 8; ++i) {
    int off = (t + i * 512) * 4;
    *(float4*)&Wl[off] = *(const float4*)&W[off];
  }
  __syncthreads();

  const int wave = t >> 6, lane = t & 63;
  const int row0 = blockIdx.x * 128 + wave * 16;

#pragma unroll 1
  for (int g = 0; g < 4; ++g) {
    const int r0 = row0 + g * 4;
    int rr0 = r0 + 0; if (rr0 > NN - 1) rr0 = NN - 1;   // clamp reads
    int rr1 = r0 + 1; if (rr1 > NN - 1) rr1 = NN - 1;
    int rr2 = r0 + 2; if (rr2 > NN - 1) rr2 = NN - 1;
    int rr3 = r0 + 3; if (rr3 > NN - 1) rr3 = NN - 1;
    rr0 = __builtin_amdgcn_readfirstlane(rr0);
    rr1 = __builtin_amdgcn_readfirstlane(rr1);
    rr2 = __builtin_amdgcn_readfirstlane(rr2);
    rr3 = __builtin_amdgcn_readfirstlane(rr3);
    const u32* A0 = Ab + (size_t)rr0 * NW;
    const u32* A1 = Ab + (size_t)rr1 * NW;
    const u32* A2 = Ab + (size_t)rr2 * NW;
    const u32* A3 = Ab + (size_t)rr3 * NW;

    float a0x = 0.f, a0y = 0.f, a1x = 0.f, a1y = 0.f;
    float a2x = 0.f, a2y = 0.f, a3x = 0.f, a3y = 0.f;

#pragma unroll 1
    for (int kc = 0; kc < D; kc += 8) {
      const uint4 q0 = *(const uint4*)(A0 + (kc >> 1));
      const uint4 q1 = *(const uint4*)(A1 + (kc >> 1));
      const uint4 q2 = *(const uint4*)(A2 + (kc >> 1));
      const uint4 q3 = *(const uint4*)(A3 + (kc >> 1));
#pragma unroll
      for (int p = 0; p < 4; ++p) {
        const u32 w0 = p == 0 ? q0.x : p == 1 ? q0.y : p == 2 ? q0.z : q0.w;
        const u32 w1 = p == 0 ? q1.x : p == 1 ? q1.y : p == 2 ? q1.z : q1.w;
        const u32 w2 = p == 0 ? q2.x : p == 1 ? q2.y : p == 2 ? q2.z : q2.w;
        const u32 w3 = p == 0 ? q3.x : p == 1 ? q3.y : p == 2 ? q3.z : q3.w;
        const int k0 = kc + 2 * p;
        const float2 wv0 = *(const float2*)&Wl[k0 * D + 2 * lane];
        const float2 wv1 = *(const float2*)&Wl[(k0 + 1) * D + 2 * lane];
        float e;
        e = blo(w0); a0x = fmaf(e, wv0.x, a0x); a0y = fmaf(e, wv0.y, a0y);
        e = bhi(w0); a0x = fmaf(e, wv1.x, a0x); a0y = fmaf(e, wv1.y, a0y);
        e = blo(w1); a1x = fmaf(e, wv0.x, a1x); a1y = fmaf(e, wv0.y, a1y);
        e = bhi(w1); a1x = fmaf(e, wv1.x, a1x); a1y = fmaf(e, wv1.y, a1y);
        e = blo(w2); a2x = fmaf(e, wv0.x, a2x); a2y = fmaf(e, wv0.y, a2y);
        e = bhi(w2); a2x = fmaf(e, wv1.x, a2x); a2y = fmaf(e, wv1.y, a2y);
        e = blo(w3); a3x = fmaf(e, wv0.x, a3x); a3y = fmaf(e, wv0.y, a3y);
        e = bhi(w3); a3x = fmaf(e, wv1.x, a3x); a3y = fmaf(e, wv1.y, a3y);
      }
    }

    if (r0 + 0 < NN) Bb[(size_t)(r0 + 0) * NW + lane] = bpack(a0x, a0y);
    if (r0 + 1 < NN) Bb[(size_t)(r0 + 1) * NW + lane] = bpack(a1x, a1y);
    if (r0 + 2 < NN) Bb[(size_t)(r0 + 2) * NW + lane] = bpack(a2x, a2y);
    if (r0 + 3 < NN) Bb[(size_t)(r0 + 3) * NW + lane] = bpack(a3x, a3y);
  }
}

// ---------------- Aggregation: one wave per node, bf16 gather, fused bias+ReLU ----

__global__ __launch_bounds__(256) void k_agg(const u32* __restrict__ hwb,
                                             const uint2* __restrict__ edat,
                                             const unsigned* __restrict__ rowptr,
                                             const float* __restrict__ dinv,
                                             const float* __restrict__ bias,
                                             u32* __restrict__ hob) {
  const int widt = (blockIdx.x * 256 + threadIdx.x) >> 6;
  if (widt >= NN) return;
  const int wid = __builtin_amdgcn_readfirstlane(widt);
  const int lane = threadIdx.x & 63;

  const float di = dinv[wid];
  const float sn = di * di;
  const u32 sv = hwb[(size_t)wid * NW + lane];
  float ax = blo(sv) * sn, ay = bhi(sv) * sn;

  const unsigned s = rowptr[wid], e = rowptr[wid + 1];
  unsigned j = s;
  for (; j + 4 <= e; j += 4) {
    const uint2 e0 = edat[j + 0];
    const uint2 e1 = edat[j + 1];
    const uint2 e2 = edat[j + 2];
    const uint2 e3 = edat[j + 3];
    const u32 u0 = hwb[(size_t)e0.x * NW + lane];
    const u32 u1 = hwb[(size_t)e1.x * NW + lane];
    const u32 u2 = hwb[(size_t)e2.x * NW + lane];
    const u32 u3 = hwb[(size_t)e3.x * NW + lane];
    const float w0 = __uint_as_float(e0.y), w1 = __uint_as_float(e1.y);
    const float w2 = __uint_as_float(e2.y), w3 = __uint_as_float(e3.y);
    ax = fmaf(w0, blo(u0), ax); ay = fmaf(w0, bhi(u0), ay);
    ax = fmaf(w1, blo(u1), ax); ay = fmaf(w1, bhi(u1), ay);
    ax = fmaf(w2, blo(u2), ax); ay = fmaf(w2, bhi(u2), ay);
    ax = fmaf(w3, blo(u3), ax); ay = fmaf(w3, bhi(u3), ay);
  }
  for (; j < e; ++j) {
    const uint2 ed = edat[j];
    const u32 u = hwb[(size_t)ed.x * NW + lane];
    const float w = __uint_as_float(ed.y);
    ax = fmaf(w, blo(u), ax); ay = fmaf(w, bhi(u), ay);
  }

  const float2 b = *(const float2*)&bias[lane * 2];
  ax += b.x; ay += b.y;
  ax = ax > 0.f ? ax : 0.f;
  ay = ay > 0.f ? ay : 0.f;
  hob[(size_t)wid * NW + lane] = bpack(ax, ay);
}

// ---------------- Head GEMV: out = h @ head_W + head_b ----------------

__global__ __launch_bounds__(256) void k_head(const u32* __restrict__ hb,
                                              const float* __restrict__ hW,
                                              const float* __restrict__ hbv,
                                              float* __restrict__ out) {
  const int widt = (blockIdx.x * 256 + threadIdx.x) >> 6;
  if (widt >= NN) return;
  const int wid = __builtin_amdgcn_readfirstlane(widt);
  const int lane = threadIdx.x & 63;
  const u32 v = hb[(size_t)wid * NW + lane];
  const float2 w = *(const float2*)&hW[lane * 2];
  float sum = blo(v) * w.x + bhi(v) * w.y;
#pragma unroll
  for (int off = 32; off > 0; off >>= 1) sum += __shfl_down(sum, off, 64);
  if (lane == 0) out[wid] = sum + hbv[0];
}

// ---------------- launch ----------------

extern "C" void kernel_launch(void* const* d_in, const int* in_sizes, int n_in,
                              void* d_out, int out_size, void* d_ws, size_t ws_size,
                              hipStream_t stream) {
  const float* x   = (const float*)d_in[0];
  const int*   ei  = (const int*)d_in[1];
  const float* Ws  = (const float*)d_in[2];
  const float* bs  = (const float*)d_in[3];
  const float* hW  = (const float*)d_in[4];
  const float* hb  = (const float*)d_in[5];
  float* out = (float*)d_out;

  char* w = (char*)d_ws;
  u32*      bufA    = (u32*)w;      w += (size_t)NN * NW * 4;      // 25.6 MB (h, bf16x2)
  u32*      bufB    = (u32*)w;      w += (size_t)NN * NW * 4;      // 25.6 MB (hw, bf16x2)
  uint2*    edat    = (uint2*)w;    w += (size_t)NE * 8;           // 12.8 MB
  unsigned* rowptr  = (unsigned*)w; w += (size_t)(NN + 16) * 4;
  unsigned* deg     = (unsigned*)w; w += (size_t)NN * 4;
  unsigned* fillcnt = (unsigned*)w; w += (size_t)NN * 4;
  float*    dinv    = (float*)w;    w += (size_t)NN * 4;
  unsigned* bsum    = (unsigned*)w; w += 512 * 4;
  unsigned* boff    = (unsigned*)w; w += 512 * 4;

  const int* srcv = ei;
  const int* dstv = ei + NE;

  hipMemsetAsync(deg,     0, (size_t)NN * 4, stream);
  hipMemsetAsync(fillcnt, 0, (size_t)NN * 4, stream);

  const int NB = (NN + 255) / 256;   // 391

  k_count<<<(NE + 255) / 256, 256, 0, stream>>>(dstv, deg);
  k_dinv <<<NB, 256, 0, stream>>>(deg, dinv);
  k_cvt  <<<(NN * NW + 255) / 256, 256, 0, stream>>>(x, bufA);
  k_scan1<<<NB, 256, 0, stream>>>(deg, bsum);
  k_scan2<<<1, 512, 0, stream>>>(bsum, boff, NB);
  k_scan3<<<NB, 256, 0, stream>>>(deg, boff, rowptr);
  k_fill <<<(NE + 255) / 256, 256, 0, stream>>>(srcv, dstv, dinv, rowptr, fillcnt, edat);

  for (int l = 0; l < NL; ++l) {
    k_gemm<<<(NN + 127) / 128, 512, 0, stream>>>(bufA, Ws + (size_t)l * D * D, bufB);
    k_agg <<<(NN + 3) / 4, 256, 0, stream>>>(bufB, edat, rowptr, dinv,
                                             bs + (size_t)l * D, bufA);
  }

  k_head<<<(NN + 3) / 4, 256, 0, stream>>>(bufA, hW, hb, out);
}

// Round 5
// 410.646 us; speedup vs baseline: 13.8200x; 1.4865x over previous
//
#include <hip/hip_runtime.h>
#include <math.h>

#define NN 100000     // nodes
#define NE 1600000    // edges
#define D  128        // feature dim
#define NW 64         // u32 words per row (D/2 packed bf16x2)
#define NL 3          // layers

typedef unsigned int u32;
typedef __attribute__((ext_vector_type(8))) short bf16x8;
typedef __attribute__((ext_vector_type(4))) float f32x4;

// ---- packed bf16x2 helpers (RNE) ----
__device__ inline float blo(u32 v) { return __uint_as_float(v << 16); }
__device__ inline float bhi(u32 v) { return __uint_as_float(v & 0xffff0000u); }
__device__ inline u32 bpack(float x, float y) {
  u32 xb = __float_as_uint(x), yb = __float_as_uint(y);
  xb = (xb + 0x7fffu + ((xb >> 16) & 1u)) >> 16;
  yb = (yb + 0x7fffu + ((yb >> 16) & 1u)) & 0xffff0000u;
  return xb | yb;
}

// ---------------- degree / normalization ----------------

__global__ __launch_bounds__(256) void k_count(const int* __restrict__ dstv,
                                               unsigned* __restrict__ deg) {
  int i = blockIdx.x * 256 + threadIdx.x;
  if (i < NE) atomicAdd(&deg[dstv[i]], 1u);
}

__global__ __launch_bounds__(256) void k_dinv(const unsigned* __restrict__ deg,
                                              float* __restrict__ dinv) {
  int i = blockIdx.x * 256 + threadIdx.x;
  if (i < NN) dinv[i] = 1.0f / sqrtf((float)(deg[i] + 1u));
}

// ---------------- x -> packed bf16 ----------------

__global__ __launch_bounds__(256) void k_cvt(const float* __restrict__ x,
                                             u32* __restrict__ xb) {
  int i = blockIdx.x * 256 + threadIdx.x;
  if (i < NN * NW) {
    const float2 v = *(const float2*)&x[(size_t)i * 2];
    xb[i] = bpack(v.x, v.y);
  }
}

// ---------------- W (f32 [k][n]) -> bf16 W^T [n][k], packed u32 ----------------

__global__ __launch_bounds__(256) void k_wcvt(const float* __restrict__ Ws,
                                              u32* __restrict__ Wtb) {
  int i = blockIdx.x * 256 + threadIdx.x;   // l*8192 + n*64 + kw
  if (i >= NL * 128 * 64) return;
  const int l = i >> 13, rem = i & 8191, n = rem >> 6, kw = rem & 63;
  const float* Wp = Ws + l * (D * D);
  Wtb[i] = bpack(Wp[(2 * kw) * D + n], Wp[(2 * kw + 1) * D + n]);
}

// ---------------- CSR build: 3-stage exclusive scan ----------------

__global__ __launch_bounds__(256) void k_scan1(const unsigned* __restrict__ deg,
                                               unsigned* __restrict__ bsum) {
  __shared__ unsigned s[256];
  int t = threadIdx.x;
  int i = blockIdx.x * 256 + t;
  s[t] = (i < NN) ? deg[i] : 0u;
  __syncthreads();
  for (int off = 128; off > 0; off >>= 1) {
    if (t < off) s[t] += s[t + off];
    __syncthreads();
  }
  if (t == 0) bsum[blockIdx.x] = s[0];
}

__global__ __launch_bounds__(512) void k_scan2(const unsigned* __restrict__ bsum,
                                               unsigned* __restrict__ boff, int nb) {
  __shared__ unsigned s[512];
  int t = threadIdx.x;
  unsigned v = (t < nb) ? bsum[t] : 0u;
  s[t] = v;
  __syncthreads();
  for (int off = 1; off < 512; off <<= 1) {
    unsigned x = (t >= off) ? s[t - off] : 0u;
    __syncthreads();
    s[t] += x;
    __syncthreads();
  }
  if (t < nb) boff[t] = s[t] - v;   // exclusive
}

__global__ __launch_bounds__(256) void k_scan3(const unsigned* __restrict__ deg,
                                               const unsigned* __restrict__ boff,
                                               unsigned* __restrict__ rowptr) {
  __shared__ unsigned s[256];
  int t = threadIdx.x;
  int i = blockIdx.x * 256 + t;
  unsigned v = (i < NN) ? deg[i] : 0u;
  s[t] = v;
  __syncthreads();
  for (int off = 1; off < 256; off <<= 1) {
    unsigned x = (t >= off) ? s[t - off] : 0u;
    __syncthreads();
    s[t] += x;
    __syncthreads();
  }
  unsigned excl = s[t] - v + boff[blockIdx.x];
  if (i <= NN) rowptr[i] = excl;    // i==NN lands exactly on total == NE
}

__global__ __launch_bounds__(256) void k_fill(const int* __restrict__ srcv,
                                              const int* __restrict__ dstv,
                                              const float* __restrict__ dinv,
                                              const unsigned* __restrict__ rowptr,
                                              unsigned* __restrict__ fillcnt,
                                              uint2* __restrict__ edat) {
  int i = blockIdx.x * 256 + threadIdx.x;
  if (i >= NE) return;
  int d = dstv[i];
  int s = srcv[i];
  unsigned pos = rowptr[d] + atomicAdd(&fillcnt[d], 1u);
  uint2 v; v.x = (u32)s; v.y = __float_as_uint(dinv[s] * dinv[d]);
  edat[pos] = v;   // single 8B scattered write
}

// ---------------- GEMM: hw = h @ W  (bf16 MFMA, W^T in swizzled LDS) ----------
// 512 threads (8 waves), 128 rows/block. Per wave: 16 rows x 128 cols via
// 32x mfma_f32_16x16x32_bf16. A frag: row=lane&15, k=(lane>>4)*8+j (m89/m91
// layout). B frag from LDS W^T[n][k], XOR-swizzled (byte ^= (n&7)<<4) on both
// write and read (rule #21). D: col=lane&15, row=(lane>>4)*4+reg. Epilogue
// packs col pairs via shfl_xor(1) into bf16x2 words.

__global__ __launch_bounds__(512, 4) void k_gemm(const u32* __restrict__ Ab,
                                                 const u32* __restrict__ Wtb,
                                                 u32* __restrict__ Bb) {
  __shared__ u32 Wl[128 * 64];   // 32 KB
  const int t = threadIdx.x;
#pragma unroll
  for (int i = 0; i < 4; ++i) {
    const int idx = (t + i * 512) * 4;          // u32 index of a 16B chunk
    const uint4 v = *(const uint4*)(Wtb + idx);
    const int byte = idx * 4;
    const int sw = byte ^ (((byte >> 8) & 7) << 4);
    *(uint4*)((char*)Wl + sw) = v;
  }
  __syncthreads();

  const int wave = t >> 6, lane = t & 63;
  const int hi = lane >> 4;                     // 0..3
  const int lo = lane & 15;
  int row = blockIdx.x * 128 + wave * 16 + lo;
  const int rowc = row < NN ? row : NN - 1;     // clamp reads, guard writes

  bf16x8 af[4];
#pragma unroll
  for (int ks = 0; ks < 4; ++ks)
    af[ks] = *(const bf16x8*)(Ab + (size_t)rowc * NW + ks * 16 + hi * 4);

  f32x4 acc[8];
#pragma unroll
  for (int ct = 0; ct < 8; ++ct) acc[ct] = (f32x4){0.f, 0.f, 0.f, 0.f};

#pragma unroll
  for (int ks = 0; ks < 4; ++ks) {
#pragma unroll
    for (int ct = 0; ct < 8; ++ct) {
      const int n = ct * 16 + lo;
      const int addr = (n * 256 + ks * 64 + hi * 16) ^ ((n & 7) << 4);
      const bf16x8 bf = *(const bf16x8*)((const char*)Wl + addr);
      acc[ct] = __builtin_amdgcn_mfma_f32_16x16x32_bf16(af[ks], bf, acc[ct], 0, 0, 0);
    }
  }

  const int rbase = blockIdx.x * 128 + wave * 16 + hi * 4;
  const bool even = (lane & 1) == 0;
  const int wcol = lo >> 1;                     // word index within ct's 8
#pragma unroll
  for (int ct = 0; ct < 8; ++ct) {
    float p0 = __shfl_xor(acc[ct][0], 1, 64);
    float p1 = __shfl_xor(acc[ct][1], 1, 64);
    float p2 = __shfl_xor(acc[ct][2], 1, 64);
    float p3 = __shfl_xor(acc[ct][3], 1, 64);
    const u32 wA = even ? bpack(acc[ct][0], p0) : bpack(p2, acc[ct][2]);
    const u32 wB = even ? bpack(acc[ct][1], p1) : bpack(p3, acc[ct][3]);
    const int rA = rbase + (even ? 0 : 2);
    if (rA < NN)     Bb[(size_t)rA * NW + ct * 8 + wcol] = wA;
    if (rA + 1 < NN) Bb[(size_t)(rA + 1) * NW + ct * 8 + wcol] = wB;
  }
}

// ---------------- Aggregation: one wave per node, bf16 gather, fused bias+ReLU ----

__global__ __launch_bounds__(256) void k_agg(const u32* __restrict__ hwb,
                                             const uint2* __restrict__ edat,
                                             const unsigned* __restrict__ rowptr,
                                             const float* __restrict__ dinv,
                                             const float* __restrict__ bias,
                                             u32* __restrict__ hob) {
  const int widt = (blockIdx.x * 256 + threadIdx.x) >> 6;
  if (widt >= NN) return;
  const int wid = __builtin_amdgcn_readfirstlane(widt);
  const int lane = threadIdx.x & 63;

  const float di = dinv[wid];
  const float sn = di * di;
  const u32 sv = hwb[(size_t)wid * NW + lane];
  float ax = blo(sv) * sn, ay = bhi(sv) * sn;

  const unsigned s = rowptr[wid], e = rowptr[wid + 1];
  unsigned j = s;
  for (; j + 8 <= e; j += 8) {
    uint2 ed[8];
    u32 u[8];
#pragma unroll
    for (int q = 0; q < 8; ++q) ed[q] = edat[j + q];
#pragma unroll
    for (int q = 0; q < 8; ++q) u[q] = hwb[(size_t)ed[q].x * NW + lane];
#pragma unroll
    for (int q = 0; q < 8; ++q) {
      const float w = __uint_as_float(ed[q].y);
      ax = fmaf(w, blo(u[q]), ax); ay = fmaf(w, bhi(u[q]), ay);
    }
  }
  for (; j + 4 <= e; j += 4) {
    uint2 ed[4];
    u32 u[4];
#pragma unroll
    for (int q = 0; q < 4; ++q) ed[q] = edat[j + q];
#pragma unroll
    for (int q = 0; q < 4; ++q) u[q] = hwb[(size_t)ed[q].x * NW + lane];
#pragma unroll
    for (int q = 0; q < 4; ++q) {
      const float w = __uint_as_float(ed[q].y);
      ax = fmaf(w, blo(u[q]), ax); ay = fmaf(w, bhi(u[q]), ay);
    }
  }
  for (; j < e; ++j) {
    const uint2 ed = edat[j];
    const u32 u = hwb[(size_t)ed.x * NW + lane];
    const float w = __uint_as_float(ed.y);
    ax = fmaf(w, blo(u), ax); ay = fmaf(w, bhi(u), ay);
  }

  const float2 b = *(const float2*)&bias[lane * 2];
  ax += b.x; ay += b.y;
  ax = ax > 0.f ? ax : 0.f;
  ay = ay > 0.f ? ay : 0.f;
  hob[(size_t)wid * NW + lane] = bpack(ax, ay);
}

// ---------------- Head GEMV: out = h @ head_W + head_b ----------------

__global__ __launch_bounds__(256) void k_head(const u32* __restrict__ hb,
                                              const float* __restrict__ hW,
                                              const float* __restrict__ hbv,
                                              float* __restrict__ out) {
  const int widt = (blockIdx.x * 256 + threadIdx.x) >> 6;
  if (widt >= NN) return;
  const int wid = __builtin_amdgcn_readfirstlane(widt);
  const int lane = threadIdx.x & 63;
  const u32 v = hb[(size_t)wid * NW + lane];
  const float2 w = *(const float2*)&hW[lane * 2];
  float sum = blo(v) * w.x + bhi(v) * w.y;
#pragma unroll
  for (int off = 32; off > 0; off >>= 1) sum += __shfl_down(sum, off, 64);
  if (lane == 0) out[wid] = sum + hbv[0];
}

// ---------------- launch ----------------

extern "C" void kernel_launch(void* const* d_in, const int* in_sizes, int n_in,
                              void* d_out, int out_size, void* d_ws, size_t ws_size,
                              hipStream_t stream) {
  const float* x   = (const float*)d_in[0];
  const int*   ei  = (const int*)d_in[1];
  const float* Ws  = (const float*)d_in[2];
  const float* bs  = (const float*)d_in[3];
  const float* hW  = (const float*)d_in[4];
  const float* hb  = (const float*)d_in[5];
  float* out = (float*)d_out;

  char* w = (char*)d_ws;
  u32*      bufA    = (u32*)w;      w += (size_t)NN * NW * 4;      // 25.6 MB (h)
  u32*      bufB    = (u32*)w;      w += (size_t)NN * NW * 4;      // 25.6 MB (hw)
  uint2*    edat    = (uint2*)w;    w += (size_t)NE * 8;           // 12.8 MB
  u32*      Wtb     = (u32*)w;      w += (size_t)NL * 128 * 64 * 4; // 96 KB
  unsigned* rowptr  = (unsigned*)w; w += (size_t)(NN + 16) * 4;
  unsigned* deg     = (unsigned*)w; w += (size_t)NN * 4;
  unsigned* fillcnt = (unsigned*)w; w += (size_t)NN * 4;
  float*    dinv    = (float*)w;    w += (size_t)NN * 4;
  unsigned* bsum    = (unsigned*)w; w += 512 * 4;
  unsigned* boff    = (unsigned*)w; w += 512 * 4;

  const int* srcv = ei;
  const int* dstv = ei + NE;

  hipMemsetAsync(deg,     0, (size_t)NN * 4, stream);
  hipMemsetAsync(fillcnt, 0, (size_t)NN * 4, stream);

  const int NB = (NN + 255) / 256;   // 391

  k_count<<<(NE + 255) / 256, 256, 0, stream>>>(dstv, deg);
  k_dinv <<<NB, 256, 0, stream>>>(deg, dinv);
  k_cvt  <<<(NN * NW + 255) / 256, 256, 0, stream>>>(x, bufA);
  k_wcvt <<<(NL * 128 * 64 + 255) / 256, 256, 0, stream>>>(Ws, Wtb);
  k_scan1<<<NB, 256, 0, stream>>>(deg, bsum);
  k_scan2<<<1, 512, 0, stream>>>(bsum, boff, NB);
  k_scan3<<<NB, 256, 0, stream>>>(deg, boff, rowptr);
  k_fill <<<(NE + 255) / 256, 256, 0, stream>>>(srcv, dstv, dinv, rowptr, fillcnt, edat);

  for (int l = 0; l < NL; ++l) {
    k_gemm<<<(NN + 127) / 128, 512, 0, stream>>>(bufA, Wtb + (size_t)l * 128 * 64, bufB);
    k_agg <<<(NN + 3) / 4, 256, 0, stream>>>(bufB, edat, rowptr, dinv,
                                             bs + (size_t)l * D, bufA);
  }

  k_head<<<(NN + 3) / 4, 256, 0, stream>>>(bufA, hW, hb, out);
}